// Round 15
// baseline (819.268 us; speedup 1.0000x reference)
//
#include <hip/hip_runtime.h>
#include <hip/hip_bf16.h>

namespace {

typedef _Float16 h16;
typedef _Float16 f16x8 __attribute__((ext_vector_type(8)));
typedef _Float16 f16x4 __attribute__((ext_vector_type(4)));
typedef _Float16 f16x2 __attribute__((ext_vector_type(2)));
typedef float    f32x4 __attribute__((ext_vector_type(4)));
typedef unsigned long long u64;

constexpr int T_SEQ  = 512;
constexpr int B_SZ   = 1024;
constexpr int H_DIM  = 128;
constexpr int ROWS   = 16;           // batch rows per group (MFMA N-tile)
constexpr int NT     = 512;          // 8 waves
constexpr int NGRP   = B_SZ / ROWS;  // 64 groups -> 128 blocks
constexpr int CHUNK  = 32;           // steps per handshake
constexpr int RING_C = 4;            // chunks in the xg ring
constexpr int RING_T = RING_C * CHUNK;  // 128 steps

// xg ring: [part(3)][t mod 128][group][tid] u64 (f16x4 pre-gate values).
// Producer lane tid and consumer lane tid hold the SAME (batch,gate) element
// (identical D-layout), so handoff is positional: fully coalesced both ways.
__device__ __forceinline__ size_t xg_idx(int p, int t, int g, int tid) {
  return ((size_t)(p * RING_T + (t & (RING_T - 1))) * NGRP + g) * 512 + tid;
}

__device__ __forceinline__ void spin_ge(int* f, int v) {
  while (__hip_atomic_load(f, __ATOMIC_ACQUIRE, __HIP_MEMORY_SCOPE_AGENT) < v)
    __builtin_amdgcn_s_sleep(2);
}

// ---------------- producer: layer-0 + l1 input GEMM (xg) ----------------
__device__ void prod_body(char* smem_raw,
                          const float* __restrict__ xin,
                          const float* __restrict__ w_ih0,
                          const float* __restrict__ w_hh0,
                          const float* __restrict__ b_ih0,
                          const float* __restrict__ b_hh0,
                          const float* __restrict__ w_ih1,
                          const float* __restrict__ b_ih1,
                          const float* __restrict__ b_hh1,
                          u64* __restrict__ xgq,
                          int* __restrict__ pflag, int* __restrict__ cflag,
                          const int g)
{
  constexpr int KSH = 4, KSX = 2;
  constexpr int ROWP = H_DIM + 64 + 8;   // r5/r12-proven pad
  auto hx = reinterpret_cast<h16 (*)[ROWS][ROWP]>(smem_raw);

  const int tid = threadIdx.x;
  const int wv  = tid >> 6;
  const int ln  = tid & 63;
  const int q   = ln >> 4;
  const int lr  = ln & 15;
  const int r0  = g * ROWS;
  const int j0  = wv * 16 + q * 4;

  auto ldw = [](const float* pw) {
    const float4 v0 = *(const float4*)(pw);
    const float4 v1 = *(const float4*)(pw + 4);
    f16x8 f;
    f[0]=(h16)v0.x; f[1]=(h16)v0.y; f[2]=(h16)v0.z; f[3]=(h16)v0.w;
    f[4]=(h16)v1.x; f[5]=(h16)v1.y; f[6]=(h16)v1.z; f[7]=(h16)v1.w;
    return f;
  };

  // weights: l0 recurrence (wA0), l0 input (wB0), l1 input (wI1)
  f16x8 wA0[3][KSH], wB0[3][KSX], wI1[3][KSH];
  #pragma unroll
  for (int p = 0; p < 3; ++p) {
    const int gr = p * H_DIM + wv * 16 + lr;
    #pragma unroll
    for (int ks = 0; ks < KSH; ++ks) {
      wA0[p][ks] = ldw(w_hh0 + (size_t)gr * H_DIM + ks * 32 + q * 8);
      wI1[p][ks] = ldw(w_ih1 + (size_t)gr * H_DIM + ks * 32 + q * 8);
    }
    #pragma unroll
    for (int ks = 0; ks < KSX; ++ks)
      wB0[p][ks] = ldw(w_ih0 + (size_t)gr * 64 + ks * 32 + q * 8);
  }

  // biases: l0 C-init; xg C-init (full r/z bias of l1; n gets b_ih1 only)
  f32x4 bR0, bZ0, bNx0, bNh0, xbR, xbZ, xbN;
  {
    const float4 ir  = *(const float4*)&b_ih0[j0];
    const float4 hr  = *(const float4*)&b_hh0[j0];
    const float4 iz  = *(const float4*)&b_ih0[H_DIM + j0];
    const float4 hz  = *(const float4*)&b_hh0[H_DIM + j0];
    const float4 in_ = *(const float4*)&b_ih0[2 * H_DIM + j0];
    const float4 hn  = *(const float4*)&b_hh0[2 * H_DIM + j0];
    bR0[0]=ir.x+hr.x; bR0[1]=ir.y+hr.y; bR0[2]=ir.z+hr.z; bR0[3]=ir.w+hr.w;
    bZ0[0]=iz.x+hz.x; bZ0[1]=iz.y+hz.y; bZ0[2]=iz.z+hz.z; bZ0[3]=iz.w+hz.w;
    bNx0[0]=in_.x; bNx0[1]=in_.y; bNx0[2]=in_.z; bNx0[3]=in_.w;
    bNh0[0]=hn.x;  bNh0[1]=hn.y;  bNh0[2]=hn.z;  bNh0[3]=hn.w;
    const float4 jr  = *(const float4*)&b_ih1[j0];
    const float4 kr  = *(const float4*)&b_hh1[j0];
    const float4 jz  = *(const float4*)&b_ih1[H_DIM + j0];
    const float4 kz  = *(const float4*)&b_hh1[H_DIM + j0];
    const float4 jn  = *(const float4*)&b_ih1[2 * H_DIM + j0];
    xbR[0]=jr.x+kr.x; xbR[1]=jr.y+kr.y; xbR[2]=jr.z+kr.z; xbR[3]=jr.w+kr.w;
    xbZ[0]=jz.x+kz.x; xbZ[1]=jz.y+kz.y; xbZ[2]=jz.z+kz.z; xbZ[3]=jz.w+kz.w;
    xbN[0]=jn.x; xbN[1]=jn.y; xbN[2]=jn.z; xbN[3]=jn.w;
  }

  const int sr = tid >> 5;   // 0..15
  const int si = tid & 31;   // 0..31

  {
    f16x4 z; z[0]=z[1]=z[2]=z[3] = (h16)0.f;
    *(f16x4*)&hx[0][sr][si * 4] = z;     // h1(-1) = 0
  }
  f16x4 h_old; h_old[0]=h_old[1]=h_old[2]=h_old[3] = (h16)0.f;

  f16x2 sA, sB;
  {
    const float2 v0 = *(const float2*)(xin + ((size_t)(r0 + sr) * T_SEQ + 0) * 64 + si * 2);
    f16x2 s0; s0[0] = (h16)v0.x; s0[1] = (h16)v0.y;
    *(f16x2*)&hx[0][sr][H_DIM + si * 2] = s0;
    const float2 v1 = *(const float2*)(xin + ((size_t)(r0 + sr) * T_SEQ + 1) * 64 + si * 2);
    sA[0] = (h16)v1.x; sA[1] = (h16)v1.y;
  }
  __syncthreads();

  auto pstep = [&](int t, int cur, f16x2& s_use, f16x2& s_load) {
    // ring back-pressure: entering chunk c needs consumer done with c-4
    if ((t & (CHUNK - 1)) == 0 && t >= RING_T)
      spin_ge(cflag, t / CHUNK - (RING_C - 1));

    f16x8 bh[KSH], bx[KSX];
    #pragma unroll
    for (int ks = 0; ks < KSH; ++ks) bh[ks] = *(const f16x8*)&hx[cur][lr][ks * 32 + q * 8];
    #pragma unroll
    for (int ks = 0; ks < KSX; ++ks) bx[ks] = *(const f16x8*)&hx[cur][lr][H_DIM + ks * 32 + q * 8];

    {  // prefetch x(t+2)
      const int tt = (t + 2 < T_SEQ) ? t + 2 : T_SEQ - 1;
      const float2 v = *(const float2*)(xin + ((size_t)(r0 + sr) * T_SEQ + tt) * 64 + si * 2);
      s_load[0] = (h16)v.x; s_load[1] = (h16)v.y;
    }

    // 7 independent chains: l0 (aR,aZ,aNh,aNx) + l1-input xg (xR,xZ,xN)
    f32x4 aR = bR0, aZ = bZ0, aNh = bNh0, aNx = bNx0;
    f32x4 xR = xbR, xZ = xbZ, xN = xbN;
    #pragma unroll
    for (int ks = 0; ks < KSH; ++ks) {
      aR  = __builtin_amdgcn_mfma_f32_16x16x32_f16(wA0[0][ks], bh[ks], aR,  0, 0, 0);
      aZ  = __builtin_amdgcn_mfma_f32_16x16x32_f16(wA0[1][ks], bh[ks], aZ,  0, 0, 0);
      aNh = __builtin_amdgcn_mfma_f32_16x16x32_f16(wA0[2][ks], bh[ks], aNh, 0, 0, 0);
      xR  = __builtin_amdgcn_mfma_f32_16x16x32_f16(wI1[0][ks], bh[ks], xR,  0, 0, 0);
      xZ  = __builtin_amdgcn_mfma_f32_16x16x32_f16(wI1[1][ks], bh[ks], xZ,  0, 0, 0);
      xN  = __builtin_amdgcn_mfma_f32_16x16x32_f16(wI1[2][ks], bh[ks], xN,  0, 0, 0);
    }
    #pragma unroll
    for (int c = 0; c < KSX; ++c) {
      aR  = __builtin_amdgcn_mfma_f32_16x16x32_f16(wB0[0][c], bx[c], aR,  0, 0, 0);
      aZ  = __builtin_amdgcn_mfma_f32_16x16x32_f16(wB0[1][c], bx[c], aZ,  0, 0, 0);
      aNx = __builtin_amdgcn_mfma_f32_16x16x32_f16(wB0[2][c], bx[c], aNx, 0, 0, 0);
    }

    // NOTE: xg published uses h1(t-1) -> this is xg for l1 step t-1?  No:
    // bh here IS h1(t-1)... l1 step t needs xg1(t) = h1(t) @ w_ih1.
    // We publish with index t-?  Resolve: xg computed from bh=h1(t-1) is
    // l1's input for step t-1.  Publish at (t-1)... but t-1 at t=0 is -1.
    // Simpler: shift — publish xg computed in step t under index t-? ...
    // We instead note l1 consumes xg(t)=h1(t)@W.  h1(t) is this step's
    // OUTPUT (nv4).  Its frags are in hx[cur^1] next step.  So the xg we
    // can compute from bh (h1(t-1)) belongs to l1 step t-1.  We therefore
    // publish under index (t-1); step 0's xg(-1) is unused, and after the
    // loop an epilogue publishes xg(511) from h1(511).
    f16x4 nv4;
    {
      float hnv[4];
      #pragma unroll
      for (int i = 0; i < 4; ++i) {
        const float rg = __builtin_amdgcn_rcpf(1.f + __expf(-aR[i]));
        const float zg = __builtin_amdgcn_rcpf(1.f + __expf(-aZ[i]));
        const float na = aNx[i] + rg * aNh[i];
        const float e2 = __expf(2.f * na);
        const float ng = 1.f - 2.f * __builtin_amdgcn_rcpf(e2 + 1.f);
        const float ho = (float)h_old[i];
        const float hn = ng + zg * (ho - ng);
        hnv[i] = hn;
        nv4[i] = (h16)hn;
      }
      h_old = nv4;
    }

    if (t > 0) {
      f16x4 xr4, xz4, xn4;
      #pragma unroll
      for (int i = 0; i < 4; ++i) { xr4[i]=(h16)xR[i]; xz4[i]=(h16)xZ[i]; xn4[i]=(h16)xN[i]; }
      u64 b0, b1, b2;
      __builtin_memcpy(&b0, &xr4, 8); __builtin_memcpy(&b1, &xz4, 8); __builtin_memcpy(&b2, &xn4, 8);
      __hip_atomic_store(&xgq[xg_idx(0, t - 1, g, tid)], b0, __ATOMIC_RELAXED, __HIP_MEMORY_SCOPE_AGENT);
      __hip_atomic_store(&xgq[xg_idx(1, t - 1, g, tid)], b1, __ATOMIC_RELAXED, __HIP_MEMORY_SCOPE_AGENT);
      __hip_atomic_store(&xgq[xg_idx(2, t - 1, g, tid)], b2, __ATOMIC_RELAXED, __HIP_MEMORY_SCOPE_AGENT);
    }

    *(f16x4*)&hx[cur ^ 1][lr][j0] = nv4;
    *(f16x2*)&hx[cur ^ 1][sr][H_DIM + si * 2] = s_use;

    // publish complete chunks of xg: after step t we have xg(0..t-1);
    // chunk c complete when t-1 == c*32+31 i.e. t == (c+1)*32 -> gate below
    if ((t & (CHUNK - 1)) == 0 && t > 0) __threadfence();
    __syncthreads();
    if ((t & (CHUNK - 1)) == 0 && t > 0 && tid == 0)
      __hip_atomic_store(pflag, t / CHUNK, __ATOMIC_RELEASE, __HIP_MEMORY_SCOPE_AGENT);
  };

  #pragma unroll 1
  for (int t = 0; t < T_SEQ; t += 2) {
    pstep(t,     0, sA, sB);
    pstep(t + 1, 1, sB, sA);
  }
  // epilogue: xg(511) from h1(511) (in hx[0] after 512 steps)
  {
    f16x8 bh[KSH];
    #pragma unroll
    for (int ks = 0; ks < KSH; ++ks) bh[ks] = *(const f16x8*)&hx[0][lr][ks * 32 + q * 8];
    f32x4 xR = xbR, xZ = xbZ, xN = xbN;
    #pragma unroll
    for (int ks = 0; ks < KSH; ++ks) {
      xR = __builtin_amdgcn_mfma_f32_16x16x32_f16(wI1[0][ks], bh[ks], xR, 0, 0, 0);
      xZ = __builtin_amdgcn_mfma_f32_16x16x32_f16(wI1[1][ks], bh[ks], xZ, 0, 0, 0);
      xN = __builtin_amdgcn_mfma_f32_16x16x32_f16(wI1[2][ks], bh[ks], xN, 0, 0, 0);
    }
    f16x4 xr4, xz4, xn4;
    #pragma unroll
    for (int i = 0; i < 4; ++i) { xr4[i]=(h16)xR[i]; xz4[i]=(h16)xZ[i]; xn4[i]=(h16)xN[i]; }
    u64 b0, b1, b2;
    __builtin_memcpy(&b0, &xr4, 8); __builtin_memcpy(&b1, &xz4, 8); __builtin_memcpy(&b2, &xn4, 8);
    __hip_atomic_store(&xgq[xg_idx(0, 511, g, tid)], b0, __ATOMIC_RELAXED, __HIP_MEMORY_SCOPE_AGENT);
    __hip_atomic_store(&xgq[xg_idx(1, 511, g, tid)], b1, __ATOMIC_RELAXED, __HIP_MEMORY_SCOPE_AGENT);
    __hip_atomic_store(&xgq[xg_idx(2, 511, g, tid)], b2, __ATOMIC_RELAXED, __HIP_MEMORY_SCOPE_AGENT);
    __threadfence();
    __syncthreads();
    if (tid == 0)
      __hip_atomic_store(pflag, T_SEQ / CHUNK, __ATOMIC_RELEASE, __HIP_MEMORY_SCOPE_AGENT);
  }
}

// ---------------- consumer: layer-1 recurrence + fused FC head ----------------
__device__ void cons_body(char* smem_raw, float* headbuf,
                          const float* __restrict__ w_hh1,
                          const float* __restrict__ b_hh1,
                          const u64* __restrict__ xgq,
                          int* __restrict__ pflag, int* __restrict__ cflag,
                          const float* __restrict__ fc1_w, const float* __restrict__ fc1_b,
                          const float* __restrict__ fc2_w, const float* __restrict__ fc2_b,
                          const float* __restrict__ gamma, const float* __restrict__ beta,
                          const float* __restrict__ mean,  const float* __restrict__ var,
                          float* __restrict__ out, const int g)
{
  constexpr int KSH = 4;
  constexpr int ROWP = H_DIM + 8;
  auto hx = reinterpret_cast<h16 (*)[ROWS][ROWP]>(smem_raw);

  const int tid = threadIdx.x;
  const int wv  = tid >> 6;
  const int ln  = tid & 63;
  const int q   = ln >> 4;
  const int lr  = ln & 15;
  const int r0  = g * ROWS;
  const int j0  = wv * 16 + q * 4;

  auto ldw = [](const float* pw) {
    const float4 v0 = *(const float4*)(pw);
    const float4 v1 = *(const float4*)(pw + 4);
    f16x8 f;
    f[0]=(h16)v0.x; f[1]=(h16)v0.y; f[2]=(h16)v0.z; f[3]=(h16)v0.w;
    f[4]=(h16)v1.x; f[5]=(h16)v1.y; f[6]=(h16)v1.z; f[7]=(h16)v1.w;
    return f;
  };

  f16x8 wA1[3][KSH];
  #pragma unroll
  for (int p = 0; p < 3; ++p) {
    const int gr = p * H_DIM + wv * 16 + lr;
    #pragma unroll
    for (int ks = 0; ks < KSH; ++ks)
      wA1[p][ks] = ldw(w_hh1 + (size_t)gr * H_DIM + ks * 32 + q * 8);
  }
  f32x4 bNh1;   // n-gate b_hh1 (r/z biases are inside xg)
  {
    const float4 hn = *(const float4*)&b_hh1[2 * H_DIM + j0];
    bNh1[0]=hn.x; bNh1[1]=hn.y; bNh1[2]=hn.z; bNh1[3]=hn.w;
  }

  {
    f16x4 z; z[0]=z[1]=z[2]=z[3] = (h16)0.f;
    *(f16x4*)&hx[0][tid >> 5][(tid & 31) * 4] = z;   // h2(-1) = 0
  }
  f16x4 h_old; h_old[0]=h_old[1]=h_old[2]=h_old[3] = (h16)0.f;

  auto load_xg = [&](int t, f16x4* d) {
    const u64 b0 = __hip_atomic_load(&xgq[xg_idx(0, t, g, tid)], __ATOMIC_RELAXED, __HIP_MEMORY_SCOPE_AGENT);
    const u64 b1 = __hip_atomic_load(&xgq[xg_idx(1, t, g, tid)], __ATOMIC_RELAXED, __HIP_MEMORY_SCOPE_AGENT);
    const u64 b2 = __hip_atomic_load(&xgq[xg_idx(2, t, g, tid)], __ATOMIC_RELAXED, __HIP_MEMORY_SCOPE_AGENT);
    __builtin_memcpy(&d[0], &b0, 8);
    __builtin_memcpy(&d[1], &b1, 8);
    __builtin_memcpy(&d[2], &b2, 8);
  };

  spin_ge(pflag, 1);            // chunk 0 (xg 0..31) ready
  f16x4 X0[3], X1[3];
  load_xg(0, X0);
  load_xg(1, X1);
  __syncthreads();

  auto cstep = [&](int t, int cur, f16x4* Xuse) {
    f16x8 bh2[KSH];
    #pragma unroll
    for (int ks = 0; ks < KSH; ++ks) bh2[ks] = *(const f16x8*)&hx[cur][lr][ks * 32 + q * 8];

    // 3 recurrence chains (zero/bias init; xg merged at gate time)
    f32x4 rR = (f32x4)(0.f), rZ = (f32x4)(0.f), rNh = bNh1;
    #pragma unroll
    for (int ks = 0; ks < KSH; ++ks) {
      rR  = __builtin_amdgcn_mfma_f32_16x16x32_f16(wA1[0][ks], bh2[ks], rR,  0, 0, 0);
      rZ  = __builtin_amdgcn_mfma_f32_16x16x32_f16(wA1[1][ks], bh2[ks], rZ,  0, 0, 0);
      rNh = __builtin_amdgcn_mfma_f32_16x16x32_f16(wA1[2][ks], bh2[ks], rNh, 0, 0, 0);
    }

    f16x4 nv4; float hnv[4];
    #pragma unroll
    for (int i = 0; i < 4; ++i) {
      const float rg = __builtin_amdgcn_rcpf(1.f + __expf(-((float)Xuse[0][i] + rR[i])));
      const float zg = __builtin_amdgcn_rcpf(1.f + __expf(-((float)Xuse[1][i] + rZ[i])));
      const float na = (float)Xuse[2][i] + rg * rNh[i];
      const float e2 = __expf(2.f * na);
      const float ng = 1.f - 2.f * __builtin_amdgcn_rcpf(e2 + 1.f);
      const float ho = (float)h_old[i];
      const float hn = ng + zg * (ho - ng);
      hnv[i] = hn;
      nv4[i] = (h16)hn;
    }
    h_old = nv4;
    *(f16x4*)&hx[cur ^ 1][lr][j0] = nv4;

    // refill Xuse with xg(t+2) after use; chunk-gated at boundaries
    if (t + 2 < T_SEQ) {
      if (((t + 2) & (CHUNK - 1)) == 0)
        spin_ge(pflag, (t + 2) / CHUNK + 1);
      load_xg(t + 2, Xuse);
    }

    if (t == T_SEQ - 1) {
      // fused FC head for this block's 16 rows
      float* h2f = headbuf;              // [16][128]
      float* act = headbuf + 16 * 128;   // [16][64]
      #pragma unroll
      for (int i = 0; i < 4; ++i) h2f[lr * 128 + j0 + i] = hnv[i];
      __syncthreads();
      {
        const int row = tid >> 5;
        const float* hr = &h2f[row * 128];
        #pragma unroll
        for (int half = 0; half < 2; ++half) {
          const int j = (tid & 31) + half * 32;
          float s = fc1_b[j];
          const float4* wr = (const float4*)(fc1_w + (size_t)j * H_DIM);
          #pragma unroll
          for (int k4 = 0; k4 < H_DIM / 4; ++k4) {
            const float4 w = wr[k4];
            const float4 h = ((const float4*)hr)[k4];
            s += w.x * h.x + w.y * h.y + w.z * h.z + w.w * h.w;
          }
          s = fmaxf(s, 0.f);
          s = (s - mean[j]) * rsqrtf(var[j] + 1e-5f) * gamma[j] + beta[j];
          act[row * 64 + j] = s;
        }
      }
      __syncthreads();
      if (tid < 32) {
        const int r = tid >> 1, o = tid & 1;
        float s = fc2_b[o];
        #pragma unroll
        for (int k = 0; k < 64; ++k) s += fc2_w[(size_t)o * 64 + k] * act[r * 64 + k];
        out[(size_t)(r0 + r) * 2 + o] = s;
      }
    }
    __syncthreads();
    // release consumed chunk (all waves' loads of chunk t/32 done pre-barrier)
    if ((t & (CHUNK - 1)) == CHUNK - 1 && tid == 0)
      __hip_atomic_store(cflag, t / CHUNK + 1, __ATOMIC_RELEASE, __HIP_MEMORY_SCOPE_AGENT);
  };

  #pragma unroll 1
  for (int t = 0; t < T_SEQ; t += 2) {
    cstep(t,     0, X0);
    cstep(t + 1, 1, X1);
  }
}

__global__ __launch_bounds__(NT, 1)   // 1 block/CU: distinct CUs for prod/cons
void gru_fused(const float* __restrict__ x,
               const float* __restrict__ w_ih0, const float* __restrict__ w_hh0,
               const float* __restrict__ b_ih0, const float* __restrict__ b_hh0,
               const float* __restrict__ w_ih1, const float* __restrict__ w_hh1,
               const float* __restrict__ b_ih1, const float* __restrict__ b_hh1,
               u64* __restrict__ xgq, int* __restrict__ pflags, int* __restrict__ cflags,
               const float* __restrict__ fc1_w, const float* __restrict__ fc1_b,
               const float* __restrict__ fc2_w, const float* __restrict__ fc2_b,
               const float* __restrict__ gamma, const float* __restrict__ beta,
               const float* __restrict__ mean,  const float* __restrict__ var,
               float* __restrict__ out)
{
  __shared__ __align__(16) char smem[(size_t)2 * ROWS * (H_DIM + 64 + 8) * sizeof(h16)];
  __shared__ __align__(16) float headbuf[16 * 128 + 16 * 64];
  const int bid = blockIdx.x;
  if (bid < NGRP)
    prod_body(smem, x, w_ih0, w_hh0, b_ih0, b_hh0, w_ih1, b_ih1, b_hh1,
              xgq, &pflags[bid], &cflags[bid], bid);
  else
    cons_body(smem, headbuf, w_hh1, b_hh1, xgq,
              &pflags[bid - NGRP], &cflags[bid - NGRP],
              fc1_w, fc1_b, fc2_w, fc2_b, gamma, beta, mean, var, out, bid - NGRP);
}

} // namespace

extern "C" void kernel_launch(void* const* d_in, const int* in_sizes, int n_in,
                              void* d_out, int out_size, void* d_ws, size_t ws_size,
                              hipStream_t stream) {
  const float* x     = (const float*)d_in[0];
  const float* w_ih0 = (const float*)d_in[1];
  const float* w_hh0 = (const float*)d_in[2];
  const float* b_ih0 = (const float*)d_in[3];
  const float* b_hh0 = (const float*)d_in[4];
  const float* w_ih1 = (const float*)d_in[5];
  const float* w_hh1 = (const float*)d_in[6];
  const float* b_ih1 = (const float*)d_in[7];
  const float* b_hh1 = (const float*)d_in[8];
  const float* fc1_w = (const float*)d_in[9];
  const float* fc1_b = (const float*)d_in[10];
  const float* fc2_w = (const float*)d_in[11];
  const float* fc2_b = (const float*)d_in[12];
  const float* gamma = (const float*)d_in[13];
  const float* beta  = (const float*)d_in[14];
  const float* mean  = (const float*)d_in[15];
  const float* var   = (const float*)d_in[16];
  float* out = (float*)d_out;

  char* ws = (char*)d_ws;
  const size_t xg_bytes = (size_t)3 * RING_T * NGRP * 512 * sizeof(u64);  // 100.7 MB
  const size_t fl_bytes = (size_t)2 * NGRP * sizeof(int);
  if (ws_size < xg_bytes + fl_bytes) return;  // fail visibly

  u64* xgq    = (u64*)ws;
  int* pflags = (int*)(ws + xg_bytes);
  int* cflags = pflags + NGRP;

  hipMemsetAsync(pflags, 0, fl_bytes, stream);   // both flag arrays -> 0
  gru_fused<<<dim3(2 * NGRP), dim3(NT), 0, stream>>>(
      x, w_ih0, w_hh0, b_ih0, b_hh0, w_ih1, w_hh1, b_ih1, b_hh1,
      xgq, pflags, cflags, fc1_w, fc1_b, fc2_w, fc2_b, gamma, beta, mean, var, out);
}

// Round 16
// 643.784 us; speedup vs baseline: 1.2726x; 1.2726x over previous
//
#include <hip/hip_runtime.h>
#include <hip/hip_bf16.h>

namespace {

typedef _Float16 h16;
typedef _Float16 f16x8 __attribute__((ext_vector_type(8)));
typedef _Float16 f16x4 __attribute__((ext_vector_type(4)));
typedef _Float16 f16x2 __attribute__((ext_vector_type(2)));
typedef float    f32x4 __attribute__((ext_vector_type(4)));
typedef unsigned long long u64;

constexpr int T_SEQ = 512;
constexpr int B_SZ  = 1024;
constexpr int H_DIM = 128;
constexpr int ROWS  = 16;           // batch rows per group (MFMA N-tile)
constexpr int NT    = 512;          // 8 waves
constexpr int NGRP  = B_SZ / ROWS;  // 64 groups -> 128 blocks
constexpr int CHUNK = 32;           // steps per producer->consumer handoff

// r12/r14 cross-block pipeline with POSITIONAL handoff:
// h1q[t][g][tid] u64 = producer lane tid's D-layout f16x4 (batch lr,
// gates j0..j0+3). Producer store = ONE 512B contiguous segment per wave
// (was 16x32B scatter -> the producer-side publish cost). Consumer load is
// equally coalesced; consumer stages via hx[buf][lr][H_DIM+j0] — the same
// cheap LDS scatter the producer uses for its own h-state (r5-verified).
template <int INDIM, bool PROD>
__device__ void gru_body(char* smem_raw, float* headbuf,
                         const float* __restrict__ xin,
                         const float* __restrict__ w_ih,
                         const float* __restrict__ w_hh,
                         const float* __restrict__ b_ih,
                         const float* __restrict__ b_hh,
                         u64* __restrict__ h1q,    // [T][NGRP][512] u64
                         int* __restrict__ flag,   // this group's chunk count
                         const float* __restrict__ fc1_w,
                         const float* __restrict__ fc1_b,
                         const float* __restrict__ fc2_w,
                         const float* __restrict__ fc2_b,
                         const float* __restrict__ gamma,
                         const float* __restrict__ beta,
                         const float* __restrict__ mean,
                         const float* __restrict__ var,
                         float* __restrict__ out,  // [B][2]
                         const int g)
{
  constexpr int KSH  = H_DIM / 32;
  constexpr int KSX  = INDIM / 32;
  constexpr int ROWP = H_DIM + INDIM + 8;   // r5/r12-proven pad (16B-aligned rows)

  auto hx = reinterpret_cast<h16 (*)[ROWS][ROWP]>(smem_raw);

  const int tid = threadIdx.x;
  const int wv  = tid >> 6;
  const int ln  = tid & 63;
  const int q   = ln >> 4;
  const int lr  = ln & 15;
  const int r0  = g * ROWS;
  const int j0  = wv * 16 + q * 4;

  // ---- weights -> fp16 frags (rounds 4-12 verified layout) ----
  f16x8 wA[3][KSH], wB[3][KSX];
  #pragma unroll
  for (int p = 0; p < 3; ++p) {
    const int gr = p * H_DIM + wv * 16 + lr;
    #pragma unroll
    for (int ks = 0; ks < KSH; ++ks) {
      const float* pw = w_hh + (size_t)gr * H_DIM + ks * 32 + q * 8;
      const float4 v0 = *(const float4*)(pw);
      const float4 v1 = *(const float4*)(pw + 4);
      f16x8 f;
      f[0]=(h16)v0.x; f[1]=(h16)v0.y; f[2]=(h16)v0.z; f[3]=(h16)v0.w;
      f[4]=(h16)v1.x; f[5]=(h16)v1.y; f[6]=(h16)v1.z; f[7]=(h16)v1.w;
      wA[p][ks] = f;
    }
    #pragma unroll
    for (int ks = 0; ks < KSX; ++ks) {
      const float* pw = w_ih + (size_t)gr * INDIM + ks * 32 + q * 8;
      const float4 v0 = *(const float4*)(pw);
      const float4 v1 = *(const float4*)(pw + 4);
      f16x8 f;
      f[0]=(h16)v0.x; f[1]=(h16)v0.y; f[2]=(h16)v0.z; f[3]=(h16)v0.w;
      f[4]=(h16)v1.x; f[5]=(h16)v1.y; f[6]=(h16)v1.z; f[7]=(h16)v1.w;
      wB[p][ks] = f;
    }
  }

  // ---- biases folded into MFMA C-init ----
  f32x4 bR, bZ, bNx, bNh;
  {
    const float4 ir  = *(const float4*)&b_ih[j0];
    const float4 hr  = *(const float4*)&b_hh[j0];
    const float4 iz  = *(const float4*)&b_ih[H_DIM + j0];
    const float4 hz  = *(const float4*)&b_hh[H_DIM + j0];
    const float4 in_ = *(const float4*)&b_ih[2 * H_DIM + j0];
    const float4 hn  = *(const float4*)&b_hh[2 * H_DIM + j0];
    bR[0]=ir.x+hr.x; bR[1]=ir.y+hr.y; bR[2]=ir.z+hr.z; bR[3]=ir.w+hr.w;
    bZ[0]=iz.x+hz.x; bZ[1]=iz.y+hz.y; bZ[2]=iz.z+hz.z; bZ[3]=iz.w+hz.w;
    bNx[0]=in_.x; bNx[1]=in_.y; bNx[2]=in_.z; bNx[3]=in_.w;
    bNh[0]=hn.x;  bNh[1]=hn.y;  bNh[2]=hn.z;  bNh[3]=hn.w;
  }

  const int sr = tid >> 5;   // 0..15
  const int si = tid & 31;   // 0..31

  // ---- prologue: zero h-state in buf0 ----
  {
    f16x4 z; z[0]=z[1]=z[2]=z[3] = (h16)0.f;
    *(f16x4*)&hx[0][sr][si * 4] = z;
  }
  f16x4 h_old; h_old[0]=h_old[1]=h_old[2]=h_old[3] = (h16)0.f;

  auto load_h1 = [&](int t, f16x4& d) {   // consumer: 512B/wave single segment
    const u64 bits = __hip_atomic_load(&h1q[((size_t)t * NGRP + g) * 512 + tid],
                                       __ATOMIC_RELAXED, __HIP_MEMORY_SCOPE_AGENT);
    __builtin_memcpy(&d, &bits, 8);
  };

  f16x2 sA, sB;          // producer x ping-pong
  f16x4 cA, cB;          // consumer h1 ping-pong (2-deep)
  if constexpr (PROD) {
    const float2 v0 = *(const float2*)(xin + ((size_t)(r0 + sr) * T_SEQ + 0) * 64 + si * 2);
    f16x2 s0; s0[0] = (h16)v0.x; s0[1] = (h16)v0.y;
    *(f16x2*)&hx[0][sr][H_DIM + si * 2] = s0;
    const float2 v1 = *(const float2*)(xin + ((size_t)(r0 + sr) * T_SEQ + 1) * 64 + si * 2);
    sA[0] = (h16)v1.x; sA[1] = (h16)v1.y;
  } else {
    while (__hip_atomic_load(flag, __ATOMIC_ACQUIRE, __HIP_MEMORY_SCOPE_AGENT) < 1)
      __builtin_amdgcn_s_sleep(2);
    f16x4 s0; load_h1(0, s0);
    *(f16x4*)&hx[0][lr][H_DIM + j0] = s0;   // positional stage (D-layout slot)
    load_h1(1, cA);                         // 2-deep prologue
  }
  __syncthreads();

  auto gates = [&](const f32x4& aR, const f32x4& aZ, const f32x4& aNx2, const f32x4& aNh2,
                   f16x4& nv4, float* hnv) {
    #pragma unroll
    for (int i = 0; i < 4; ++i) {
      const float rg = __builtin_amdgcn_rcpf(1.f + __expf(-aR[i]));
      const float zg = __builtin_amdgcn_rcpf(1.f + __expf(-aZ[i]));
      const float na = aNx2[i] + rg * aNh2[i];
      const float e2 = __expf(2.f * na);
      const float ng = 1.f - 2.f * __builtin_amdgcn_rcpf(e2 + 1.f);
      const float ho = (float)h_old[i];
      const float hn = ng + zg * (ho - ng);
      hnv[i] = hn;
      nv4[i] = (h16)hn;
    }
    h_old = nv4;
  };

  auto mfma_all = [&](const f16x8* bh, const f16x8* bx,
                      f32x4& aR, f32x4& aZ, f32x4& aNh2, f32x4& aNx2) {
    aR = bR; aZ = bZ; aNh2 = bNh; aNx2 = bNx;
    #pragma unroll
    for (int ks = 0; ks < KSH; ++ks) {
      aR   = __builtin_amdgcn_mfma_f32_16x16x32_f16(wA[0][ks], bh[ks], aR, 0, 0, 0);
      aZ   = __builtin_amdgcn_mfma_f32_16x16x32_f16(wA[1][ks], bh[ks], aZ, 0, 0, 0);
      aNh2 = __builtin_amdgcn_mfma_f32_16x16x32_f16(wA[2][ks], bh[ks], aNh2, 0, 0, 0);
    }
    #pragma unroll
    for (int ks = 0; ks < KSX; ++ks) {
      aR   = __builtin_amdgcn_mfma_f32_16x16x32_f16(wB[0][ks], bx[ks], aR, 0, 0, 0);
      aZ   = __builtin_amdgcn_mfma_f32_16x16x32_f16(wB[1][ks], bx[ks], aZ, 0, 0, 0);
      aNx2 = __builtin_amdgcn_mfma_f32_16x16x32_f16(wB[2][ks], bx[ks], aNx2, 0, 0, 0);
    }
  };

  if constexpr (PROD) {
    auto pstep = [&](int t, int cur, f16x2& s_use, f16x2& s_load) {
      f16x8 bh[KSH], bx[KSX];
      #pragma unroll
      for (int ks = 0; ks < KSH; ++ks) bh[ks] = *(const f16x8*)&hx[cur][lr][ks * 32 + q * 8];
      #pragma unroll
      for (int ks = 0; ks < KSX; ++ks) bx[ks] = *(const f16x8*)&hx[cur][lr][H_DIM + ks * 32 + q * 8];

      {  // prefetch x(t+2), 2-deep
        const int tt = (t + 2 < T_SEQ) ? t + 2 : T_SEQ - 1;
        const float2 v = *(const float2*)(xin + ((size_t)(r0 + sr) * T_SEQ + tt) * 64 + si * 2);
        s_load[0] = (h16)v.x; s_load[1] = (h16)v.y;
      }

      f32x4 aR, aZ, aNh2, aNx2;
      mfma_all(bh, bx, aR, aZ, aNh2, aNx2);

      f16x4 nv4; float hnv[4];
      gates(aR, aZ, aNx2, aNh2, nv4, hnv);

      // publish: single 512B segment per wave (positional layout)
      u64 bits; __builtin_memcpy(&bits, &nv4, 8);
      __hip_atomic_store(&h1q[((size_t)t * NGRP + g) * 512 + tid], bits,
                         __ATOMIC_RELAXED, __HIP_MEMORY_SCOPE_AGENT);

      *(f16x4*)&hx[cur ^ 1][lr][j0] = nv4;
      *(f16x2*)&hx[cur ^ 1][sr][H_DIM + si * 2] = s_use;

      if ((t & (CHUNK - 1)) == CHUNK - 1) __threadfence();  // once per chunk
      __syncthreads();
      if (((t & (CHUNK - 1)) == CHUNK - 1) && tid == 0)
        __hip_atomic_store(flag, (t + 1) / CHUNK, __ATOMIC_RELEASE, __HIP_MEMORY_SCOPE_AGENT);
    };

    #pragma unroll 1
    for (int t = 0; t < T_SEQ; t += 2) {
      pstep(t,     0, sA, sB);
      pstep(t + 1, 1, sB, sA);
    }
  } else {
    auto cstep = [&](int t, int cur, f16x4& s_use, f16x4& s_load) {
      f16x8 bh[KSH], bx[KSX];
      #pragma unroll
      for (int ks = 0; ks < KSH; ++ks) bh[ks] = *(const f16x8*)&hx[cur][lr][ks * 32 + q * 8];
      #pragma unroll
      for (int ks = 0; ks < KSX; ++ks) bx[ks] = *(const f16x8*)&hx[cur][lr][H_DIM + ks * 32 + q * 8];

      // prefetch h1(t+2): chunk-gated spin only at 32-step boundaries
      if (t + 2 < T_SEQ) {
        if (((t + 2) & (CHUNK - 1)) == 0) {
          const int need = (t + 2) / CHUNK + 1;
          while (__hip_atomic_load(flag, __ATOMIC_ACQUIRE, __HIP_MEMORY_SCOPE_AGENT) < need)
            __builtin_amdgcn_s_sleep(2);
        }
        load_h1(t + 2, s_load);
      }

      f32x4 aR, aZ, aNh2, aNx2;
      mfma_all(bh, bx, aR, aZ, aNh2, aNx2);

      f16x4 nv4; float hnv[4];
      gates(aR, aZ, aNx2, aNh2, nv4, hnv);

      *(f16x4*)&hx[cur ^ 1][lr][j0] = nv4;
      if (t + 1 < T_SEQ) *(f16x4*)&hx[cur ^ 1][lr][H_DIM + j0] = s_use;  // positional stage

      if (t == T_SEQ - 1) {
        // ---- fused FC head: fc2(BN(relu(fc1(h2)))) for this block's 16 rows
        float* h2f = headbuf;              // [16][128]
        float* act = headbuf + 16 * 128;   // [16][64]
        #pragma unroll
        for (int i = 0; i < 4; ++i) h2f[lr * 128 + j0 + i] = hnv[i];
        __syncthreads();
        {
          const int row = tid >> 5;
          const float* hr = &h2f[row * 128];
          #pragma unroll
          for (int half = 0; half < 2; ++half) {
            const int j = (tid & 31) + half * 32;
            float s = fc1_b[j];
            const float4* wr = (const float4*)(fc1_w + (size_t)j * H_DIM);
            #pragma unroll
            for (int k4 = 0; k4 < H_DIM / 4; ++k4) {
              const float4 w = wr[k4];
              const float4 h = ((const float4*)hr)[k4];
              s += w.x * h.x + w.y * h.y + w.z * h.z + w.w * h.w;
            }
            s = fmaxf(s, 0.f);
            s = (s - mean[j]) * rsqrtf(var[j] + 1e-5f) * gamma[j] + beta[j];
            act[row * 64 + j] = s;
          }
        }
        __syncthreads();
        if (tid < 32) {
          const int r = tid >> 1, o = tid & 1;
          float s = fc2_b[o];
          #pragma unroll
          for (int k = 0; k < 64; ++k) s += fc2_w[(size_t)o * 64 + k] * act[r * 64 + k];
          out[(size_t)(r0 + r) * 2 + o] = s;
        }
      }
      __syncthreads();
    };

    #pragma unroll 1
    for (int t = 0; t < T_SEQ; t += 2) {
      cstep(t,     0, cA, cB);
      cstep(t + 1, 1, cB, cA);
    }
  }
}

__global__ __launch_bounds__(NT, 1)   // 1 block/CU: producers & consumers on distinct CUs
void gru_fused(const float* __restrict__ x,
               const float* __restrict__ w_ih0, const float* __restrict__ w_hh0,
               const float* __restrict__ b_ih0, const float* __restrict__ b_hh0,
               const float* __restrict__ w_ih1, const float* __restrict__ w_hh1,
               const float* __restrict__ b_ih1, const float* __restrict__ b_hh1,
               u64* __restrict__ h1q, int* __restrict__ flags,
               const float* __restrict__ fc1_w, const float* __restrict__ fc1_b,
               const float* __restrict__ fc2_w, const float* __restrict__ fc2_b,
               const float* __restrict__ gamma, const float* __restrict__ beta,
               const float* __restrict__ mean,  const float* __restrict__ var,
               float* __restrict__ out)
{
  __shared__ __align__(16) char smem[(size_t)2 * ROWS * (H_DIM + H_DIM + 8) * sizeof(h16)];
  __shared__ __align__(16) float headbuf[16 * 128 + 16 * 64];
  const int bid = blockIdx.x;
  if (bid < NGRP)
    gru_body<64, true>(smem, headbuf, x, w_ih0, w_hh0, b_ih0, b_hh0, h1q, &flags[bid],
                       nullptr, nullptr, nullptr, nullptr, nullptr, nullptr, nullptr, nullptr,
                       nullptr, bid);
  else
    gru_body<128, false>(smem, headbuf, nullptr, w_ih1, w_hh1, b_ih1, b_hh1, h1q,
                         &flags[bid - NGRP], fc1_w, fc1_b, fc2_w, fc2_b, gamma, beta,
                         mean, var, out, bid - NGRP);
}

} // namespace

extern "C" void kernel_launch(void* const* d_in, const int* in_sizes, int n_in,
                              void* d_out, int out_size, void* d_ws, size_t ws_size,
                              hipStream_t stream) {
  const float* x     = (const float*)d_in[0];
  const float* w_ih0 = (const float*)d_in[1];
  const float* w_hh0 = (const float*)d_in[2];
  const float* b_ih0 = (const float*)d_in[3];
  const float* b_hh0 = (const float*)d_in[4];
  const float* w_ih1 = (const float*)d_in[5];
  const float* w_hh1 = (const float*)d_in[6];
  const float* b_ih1 = (const float*)d_in[7];
  const float* b_hh1 = (const float*)d_in[8];
  const float* fc1_w = (const float*)d_in[9];
  const float* fc1_b = (const float*)d_in[10];
  const float* fc2_w = (const float*)d_in[11];
  const float* fc2_b = (const float*)d_in[12];
  const float* gamma = (const float*)d_in[13];
  const float* beta  = (const float*)d_in[14];
  const float* mean  = (const float*)d_in[15];
  const float* var   = (const float*)d_in[16];
  float* out = (float*)d_out;

  char* ws = (char*)d_ws;
  const size_t h1_bytes = (size_t)T_SEQ * NGRP * 512 * sizeof(u64);        // 134 MB
  const size_t fl_bytes = (size_t)NGRP * sizeof(int);
  if (ws_size < h1_bytes + fl_bytes) return;  // fail visibly

  u64* h1q   = (u64*)ws;
  int* flags = (int*)(ws + h1_bytes);

  hipMemsetAsync(flags, 0, fl_bytes, stream);   // flags start at 0 each replay
  gru_fused<<<dim3(2 * NGRP), dim3(NT), 0, stream>>>(
      x, w_ih0, w_hh0, b_ih0, b_hh0, w_ih1, w_hh1, b_ih1, b_hh1, h1q, flags,
      fc1_w, fc1_b, fc2_w, fc2_b, gamma, beta, mean, var, out);
}